// Round 8
// baseline (145.349 us; speedup 1.0000x reference)
//
#include <hip/hip_runtime.h>
#include <hip/hip_bf16.h>

#define BB 16
#define CC 64
#define NN 4096      // H*W
#define MM 1024      // pooled spatial
#define LOG2E 1.4426950408889634f

typedef unsigned short u16;
typedef unsigned int u32;
typedef __attribute__((ext_vector_type(8))) short bf16x8;
typedef __attribute__((ext_vector_type(4))) float f32x4;

__device__ inline u16 f2bf(float f) {
    union { float f; u32 u; } v; v.f = f;
    return (u16)((v.u + 0x7FFFu + ((v.u >> 16) & 1u)) >> 16);
}
__device__ inline bf16x8 ld_bf16x8(const u16* p) {
    union { uint4 u; bf16x8 b; } c; c.u = *(const uint4*)p; return c.b;
}
__device__ inline bf16x8 ld2_bf16x8(const u16* p0, const u16* p1) {
    union { uint2 u[2]; bf16x8 b; } c;
    c.u[0] = *(const uint2*)p0;
    c.u[1] = *(const uint2*)p1;
    return c.b;
}
__device__ inline u32 cvt_pk_bf16(float lo, float hi) {
    __hip_bfloat162 h = __float22bfloat162_rn(make_float2(lo, hi));
    return *(u32*)&h;
}

// ---------------------------------------------------------------------------
// Single fused kernel: 1x1 convs + 2x2 maxpool + softmax attention + output
// conv + residual. grid 512 linear; j -> (b = j%8 + 8*(j>>8), qt = (j>>3)&31)
// pins all 32 blocks of a batch to one XCD (round-robin heuristic) so the
// 1 MB batch-x stays L2-resident despite each block sweeping the whole batch.
// Block owns queries qbase = qt*128 (image rows 2qt, 2qt+1).
// Keys in 2 chunks of 512 (pooled rows 16c..16c+15); per chunk:
//   conv sweep (wave w -> 4 pooled rows): MFMA [48ch x 64] @ [64 x px],
//   pool horizontal shfl_xor(1) + vertical in-lane -> phi/gT in LDS;
//   theta (own rows, pre-scaled log2e) -> LDS when the sweep passes them
//   (block processes chunk qt>>4 FIRST so theta exists before attention).
//   attention: S^T = mfma(phi,theta); exp2 -> P B-frag in registers
//   (K-permuted); O^T += mfma(g,P); denom += mfma(ones,P). Additive across
//   chunks (no max-subtraction -> no rescale).
// Epilogue: in-lane normalize, 10KB LDS transpose, w_o MFMA + gamma + x.
// No workspace, one dispatch, 5 barriers.
// ---------------------------------------------------------------------------
__global__ __launch_bounds__(256, 2) void fused_kernel(
    const float* __restrict__ x, const float* __restrict__ w_theta,
    const float* __restrict__ w_phi, const float* __restrict__ w_g,
    const float* __restrict__ w_o, const float* __restrict__ gamma_p,
    float* __restrict__ out)
{
    __shared__ u16 phS[512 * 8];     // chunk phi [key][8], 8 KB
    __shared__ u16 gsS[32 * 520];    // chunk gT [d][512+pad8], 32.5 KB
    __shared__ u16 thS[128 * 8];     // theta*log2e for own queries, 2 KB
    __shared__ u16 oS[128 * 40];     // [q_local][d+pad8], 10 KB

    const int t = threadIdx.x, w = t >> 6, lane = t & 63;
    const int m16 = lane & 15, quad = lane >> 4;
    const int j = blockIdx.x;
    const int b  = (j & 7) + ((j >> 8) << 3);
    const int qt = (j >> 3) & 31;
    const int qbase = qt * 128;

    // ---- conv weight A-frags: f0 = theta(m16<8)/phi(m16>=8), f1/f2 = g ----
    bf16x8 A[3][2];
    {
        const float* row0 = (m16 < 8) ? (w_theta + m16 * 64) : (w_phi + (m16 - 8) * 64);
        const float* rows[3] = { row0, w_g + m16 * 64, w_g + (16 + m16) * 64 };
        #pragma unroll
        for (int f = 0; f < 3; ++f)
            #pragma unroll
            for (int kc = 0; kc < 2; ++kc) {
                const float* p = rows[f] + kc * 32 + quad * 8;
                const float4 f0 = *(const float4*)p;
                const float4 f1 = *(const float4*)(p + 4);
                union { u32 d[4]; bf16x8 v; } a;
                a.d[0] = cvt_pk_bf16(f0.x, f0.y);
                a.d[1] = cvt_pk_bf16(f0.z, f0.w);
                a.d[2] = cvt_pk_bf16(f1.x, f1.y);
                a.d[3] = cvt_pk_bf16(f1.z, f1.w);
                A[f][kc] = a.v;
            }
    }

    // ---- w_o A-frags + ones ----
    bf16x8 woA[4];
    #pragma unroll
    for (int cf = 0; cf < 4; ++cf) {
        const float* wp = w_o + (cf * 16 + m16) * 32 + quad * 8;
        const float4 f0 = *(const float4*)wp;
        const float4 f1 = *(const float4*)(wp + 4);
        union { u32 d[4]; bf16x8 v; } a;
        a.d[0] = cvt_pk_bf16(f0.x, f0.y);
        a.d[1] = cvt_pk_bf16(f0.z, f0.w);
        a.d[2] = cvt_pk_bf16(f1.x, f1.y);
        a.d[3] = cvt_pk_bf16(f1.z, f1.w);
        woA[cf] = a.v;
    }
    bf16x8 onesA;
    #pragma unroll
    for (int i = 0; i < 8; ++i) onesA[i] = (short)0x3F80;

    const float* xb = x + (size_t)b * CC * NN;
    const f32x4 zero4 = {0.f, 0.f, 0.f, 0.f};
    f32x4 oT0[2] = {zero4, zero4}, oT1[2] = {zero4, zero4}, lacc[2] = {zero4, zero4};
    bf16x8 thB[2] = {{0,0,0,0,0,0,0,0}, {0,0,0,0,0,0,0,0}};

    const int c0 = qt >> 4;   // chunk containing this block's theta rows

    for (int cc = 0; cc < 2; ++cc) {
        const int c = (cc == 0) ? c0 : 1 - c0;

        // ================= conv sweep: wave w -> pooled rows c*16+4w..+3 ====
        for (int i = 0; i < 4; ++i) {
            const int pr = c * 16 + w * 4 + i;
            for (int cg = 0; cg < 4; ++cg) {
                f32x4 f0r[2], f1r[2], f2r[2];
                #pragma unroll
                for (int r = 0; r < 2; ++r) {
                    const int px = (2 * pr + r) * 64 + cg * 16 + m16;
                    f32x4 a0 = zero4, a1 = zero4, a2 = zero4;
                    #pragma unroll
                    for (int kc = 0; kc < 2; ++kc) {
                        float xv[8];
                        #pragma unroll
                        for (int jj = 0; jj < 8; ++jj)
                            xv[jj] = xb[(size_t)(kc * 32 + quad * 8 + jj) * NN + px];
                        union { u32 d[4]; bf16x8 v; } bxf;
                        bxf.d[0] = cvt_pk_bf16(xv[0], xv[1]);
                        bxf.d[1] = cvt_pk_bf16(xv[2], xv[3]);
                        bxf.d[2] = cvt_pk_bf16(xv[4], xv[5]);
                        bxf.d[3] = cvt_pk_bf16(xv[6], xv[7]);
                        a0 = __builtin_amdgcn_mfma_f32_16x16x32_bf16(A[0][kc], bxf.v, a0, 0, 0, 0);
                        a1 = __builtin_amdgcn_mfma_f32_16x16x32_bf16(A[1][kc], bxf.v, a1, 0, 0, 0);
                        a2 = __builtin_amdgcn_mfma_f32_16x16x32_bf16(A[2][kc], bxf.v, a2, 0, 0, 0);
                    }
                    f0r[r] = a0; f1r[r] = a1; f2r[r] = a2;
                    // theta for own queries (rows 2qt,2qt+1), scaled by log2e
                    if (pr == qt && quad < 2) {
                        const int ql = r * 64 + cg * 16 + m16;
                        uint2 v;
                        v.x = cvt_pk_bf16(a0[0] * LOG2E, a0[1] * LOG2E);
                        v.y = cvt_pk_bf16(a0[2] * LOG2E, a0[3] * LOG2E);
                        *(uint2*)(thS + ql * 8 + quad * 4) = v;
                    }
                }
                // ---- 2x2 pool: horizontal shfl_xor(1), vertical in-lane ----
                float pv0[4], pv1[4], pv2[4];
                #pragma unroll
                for (int rr = 0; rr < 4; ++rr) {
                    float h0, h1;
                    h0 = f0r[0][rr]; h0 = fmaxf(h0, __shfl_xor(h0, 1, 64));
                    h1 = f0r[1][rr]; h1 = fmaxf(h1, __shfl_xor(h1, 1, 64));
                    pv0[rr] = fmaxf(h0, h1);
                    h0 = f1r[0][rr]; h0 = fmaxf(h0, __shfl_xor(h0, 1, 64));
                    h1 = f1r[1][rr]; h1 = fmaxf(h1, __shfl_xor(h1, 1, 64));
                    pv1[rr] = fmaxf(h0, h1);
                    h0 = f2r[0][rr]; h0 = fmaxf(h0, __shfl_xor(h0, 1, 64));
                    h1 = f2r[1][rr]; h1 = fmaxf(h1, __shfl_xor(h1, 1, 64));
                    pv2[rr] = fmaxf(h0, h1);
                }
                if ((m16 & 1) == 0) {
                    const int ml = (pr - c * 16) * 32 + cg * 8 + (m16 >> 1);
                    if (quad >= 2) {   // phi ch = (quad-2)*4+rr
                        uint2 v;
                        v.x = cvt_pk_bf16(pv0[0], pv0[1]);
                        v.y = cvt_pk_bf16(pv0[2], pv0[3]);
                        *(uint2*)(phS + ml * 8 + (quad - 2) * 4) = v;
                    }
                    #pragma unroll
                    for (int rr = 0; rr < 4; ++rr) {
                        gsS[(quad * 4 + rr) * 520 + ml]        = f2bf(pv1[rr]);
                        gsS[(16 + quad * 4 + rr) * 520 + ml]   = f2bf(pv2[rr]);
                    }
                }
            }
        }
        __syncthreads();

        if (cc == 0 && quad == 0) {   // theta frags now available in LDS
            thB[0] = ld_bf16x8(thS + (w * 32 + m16) * 8);
            thB[1] = ld_bf16x8(thS + (w * 32 + 16 + m16) * 8);
        }

        // ================= attention over this chunk's 512 keys ============
        #pragma unroll 4
        for (int kblk = 0; kblk < 16; ++kblk) {
            const int kb = kblk * 32;
            bf16x8 phA0 = {0, 0, 0, 0, 0, 0, 0, 0};
            bf16x8 phA1 = {0, 0, 0, 0, 0, 0, 0, 0};
            if (quad == 0) {
                phA0 = ld_bf16x8(phS + (kb + m16) * 8);
                phA1 = ld_bf16x8(phS + (kb + 16 + m16) * 8);
            }
            const u16* g0p = gsS + m16 * 520 + kb + quad * 4;
            const u16* g1p = gsS + (16 + m16) * 520 + kb + quad * 4;
            const bf16x8 gA0 = ld2_bf16x8(g0p, g0p + 16);
            const bf16x8 gA1 = ld2_bf16x8(g1p, g1p + 16);

            #pragma unroll
            for (int u = 0; u < 2; ++u) {
                const f32x4 Sa = __builtin_amdgcn_mfma_f32_16x16x32_bf16(phA0, thB[u], zero4, 0, 0, 0);
                const f32x4 Sb = __builtin_amdgcn_mfma_f32_16x16x32_bf16(phA1, thB[u], zero4, 0, 0, 0);
                union { u32 d[4]; bf16x8 v; } pb;
                pb.d[0] = cvt_pk_bf16(exp2f(Sa[0]), exp2f(Sa[1]));
                pb.d[1] = cvt_pk_bf16(exp2f(Sa[2]), exp2f(Sa[3]));
                pb.d[2] = cvt_pk_bf16(exp2f(Sb[0]), exp2f(Sb[1]));
                pb.d[3] = cvt_pk_bf16(exp2f(Sb[2]), exp2f(Sb[3]));
                oT0[u]  = __builtin_amdgcn_mfma_f32_16x16x32_bf16(gA0, pb.v, oT0[u], 0, 0, 0);
                oT1[u]  = __builtin_amdgcn_mfma_f32_16x16x32_bf16(gA1, pb.v, oT1[u], 0, 0, 0);
                lacc[u] = __builtin_amdgcn_mfma_f32_16x16x32_bf16(onesA, pb.v, lacc[u], 0, 0, 0);
            }
        }
        __syncthreads();   // before next chunk's conv overwrites phS/gsS
    }

    // ================= epilogue ===========================================
    #pragma unroll
    for (int u = 0; u < 2; ++u) {
        const float inv = 1.0f / lacc[u][0];
        u16* orow = oS + (size_t)(w * 32 + u * 16 + m16) * 40;
        uint2 a, b2;
        a.x  = cvt_pk_bf16(oT0[u][0] * inv, oT0[u][1] * inv);
        a.y  = cvt_pk_bf16(oT0[u][2] * inv, oT0[u][3] * inv);
        b2.x = cvt_pk_bf16(oT1[u][0] * inv, oT1[u][1] * inv);
        b2.y = cvt_pk_bf16(oT1[u][2] * inv, oT1[u][3] * inv);
        *(uint2*)(orow + quad * 4) = a;
        *(uint2*)(orow + 16 + quad * 4) = b2;
    }
    // oS rows are wave-private: lgkmcnt ordering suffices, no barrier needed
    const float gamma = *gamma_p;
    #pragma unroll
    for (int u = 0; u < 2; ++u) {
        const bf16x8 oB = ld_bf16x8(oS + (size_t)(w * 32 + u * 16 + m16) * 40 + quad * 8);
        #pragma unroll
        for (int cf = 0; cf < 4; ++cf) {
            const f32x4 D = __builtin_amdgcn_mfma_f32_16x16x32_bf16(woA[cf], oB, zero4, 0, 0, 0);
            #pragma unroll
            for (int rr = 0; rr < 4; ++rr) {
                const int cch = cf * 16 + quad * 4 + rr;
                const size_t adr = ((size_t)b * CC + cch) * NN + qbase + w * 32 + u * 16 + m16;
                out[adr] = gamma * D[rr] + x[adr];
            }
        }
    }
}

// ---------------------------------------------------------------------------
extern "C" void kernel_launch(void* const* d_in, const int* in_sizes, int n_in,
                              void* d_out, int out_size, void* d_ws, size_t ws_size,
                              hipStream_t stream) {
    const float* x       = (const float*)d_in[0];
    const float* w_theta = (const float*)d_in[1];
    const float* w_phi   = (const float*)d_in[2];
    const float* w_g     = (const float*)d_in[3];
    const float* w_o     = (const float*)d_in[4];
    const float* gamma   = (const float*)d_in[5];
    float* out = (float*)d_out;

    fused_kernel<<<dim3(512), 256, 0, stream>>>(x, w_theta, w_phi, w_g,
                                                w_o, gamma, out);
}